// Round 4
// baseline (452.646 us; speedup 1.0000x reference)
//
#include <hip/hip_runtime.h>
#include <hip/hip_bf16.h>
#include <math.h>

#define BATCH 16
#define NN 2048
#define FF 128
#define CC 32
#define HID 512
#define QM 512                 // m-columns per staged hT slice (quarter of NN)
#define LSTR 520               // 512 + 8 pad (1040 B LDS row stride)
#define KS2 256                // agg1 K-step (floats per row per staged tile)

typedef float v4f __attribute__((ext_vector_type(4)));
typedef float v2f __attribute__((ext_vector_type(2)));
typedef short short8 __attribute__((ext_vector_type(8)));
typedef short s4v __attribute__((ext_vector_type(4)));

__device__ __forceinline__ unsigned short f2bf(float f) {
  unsigned u = __float_as_uint(f);
  u += 0x7fffu + ((u >> 16) & 1u);
  return (unsigned short)(u >> 16);
}

__device__ __forceinline__ float elu1(float x) {
  return x > 0.f ? x : expm1f(x);
}

// ---------------------------------------------------------------------------
// k_xw1: hT1[b][c][n] = bf16( x[row][0:128] @ w1[128][32] )
// ---------------------------------------------------------------------------
__global__ __launch_bounds__(256)
void k_xw1(const float* __restrict__ src, const float* __restrict__ w,
           unsigned short* __restrict__ outT) {
  int t = threadIdx.x;
  int wv = t >> 6, l = t & 63, lo = l & 15, q = l >> 4;
  int rowt = blockIdx.x * 4 + wv;
  long row = (long)rowt * 16 + lo;

  short8 wf[FF / 32][2];
#pragma unroll
  for (int kc = 0; kc < FF / 32; ++kc)
#pragma unroll
    for (int h = 0; h < 2; ++h) {
      short8 f;
#pragma unroll
      for (int j = 0; j < 8; ++j)
        f[j] = (short)f2bf(w[(kc * 32 + q * 8 + j) * CC + h * 16 + lo]);
      wf[kc][h] = f;
    }

  v4f acc0 = {0.f, 0.f, 0.f, 0.f}, acc1 = {0.f, 0.f, 0.f, 0.f};
#pragma unroll
  for (int kc = 0; kc < FF / 32; ++kc) {
    const float* sp = src + row * FF + kc * 32 + q * 8;
    float4 a0 = *(const float4*)sp;
    float4 a1 = *(const float4*)(sp + 4);
    short8 af;
    af[0] = (short)f2bf(a0.x); af[1] = (short)f2bf(a0.y);
    af[2] = (short)f2bf(a0.z); af[3] = (short)f2bf(a0.w);
    af[4] = (short)f2bf(a1.x); af[5] = (short)f2bf(a1.y);
    af[6] = (short)f2bf(a1.z); af[7] = (short)f2bf(a1.w);
    acc0 = __builtin_amdgcn_mfma_f32_16x16x32_bf16(af, wf[kc][0], acc0, 0, 0, 0);
    acc1 = __builtin_amdgcn_mfma_f32_16x16x32_bf16(af, wf[kc][1], acc1, 0, 0, 0);
  }

  int b = rowt >> 7;
  int nbase = (rowt & 127) * 16;
#pragma unroll
  for (int r = 0; r < 4; ++r) {
    int n = nbase + q * 4 + r;
    outT[((long)b * CC + lo) * NN + n] = f2bf(acc0[r]);
    outT[((long)b * CC + 16 + lo) * NN + n] = f2bf(acc1[r]);
  }
}

// ---------------------------------------------------------------------------
// k_agg1f (R3 = R2 + stage-address fix): FULL-K aggregation + FUSED xw2.
// 512 threads (8 waves: 4 row-tiles x 2 c-halves), 2 blocks/CU -> 16 waves/CU.
// K-step 256 (1-KB-per-row DRAM bursts), single-buffered 32 KB A tile,
// loads for step s+1 in flight under step s's MFMAs (T14).
// FIX vs R2: within-row LDS byte offset is chunk*8 (8 B per 4-bf16 store),
// not chunk*16 -- chunk*16 wrote up to 512 B past `at` (LDS OOB every step).
// Epilogue: h1 = elu(acc+b1) -> LDS -> hT2 = bf16(2^-10 * h1 @ w2) directly.
// grid = 16b x 32rt = 512 blocks x 512 thr; LDS 65.2 KB.
// ---------------------------------------------------------------------------
__global__ __launch_bounds__(512, 4)
void k_agg1f(const float* __restrict__ a, unsigned char* __restrict__ afp8,
             const unsigned short* __restrict__ hT, const float* __restrict__ b1,
             const float* __restrict__ w2, unsigned short* __restrict__ hT2out) {
  __shared__ __attribute__((aligned(16))) unsigned short hs[CC * LSTR];
  __shared__ __attribute__((aligned(16))) unsigned short at[64 * KS2];

  int t = threadIdx.x;
  int bid = blockIdx.x;
  int rt = bid & 31, b = bid >> 5;
  int n0 = rt * 64;

  // stage geometry: r0 in 0..7 (uniform per wave), chunk in 0..63
  // each thread: float4 at k=chunk*4 -> 8-B bf16 store at row byte chunk*8
  int r0 = t >> 6, chunk = t & 63;
  const float* ga = a + ((long)(b * NN + n0 + r0)) * NN + chunk * 4;
  unsigned char* gao = afp8 + ((long)(b * NN + n0 + r0)) * NN + chunk * 4;
  int swb = r0 * 512 + ((chunk * 8) ^ (r0 << 4));   // swizzled byte base in at

  float4 ar[8];
  const float sc = 1024.f;

  // ---- prologue: issue A loads for step 0
#pragma unroll
  for (int j = 0; j < 8; ++j)
    ar[j] = *(const float4*)(ga + (long)j * 8 * NN);

  // stage hs slice qm=0 (4 iters x 512 thr x 16 B)
#pragma unroll
  for (int i = 0; i < 4; ++i) {
    int jj = i * 512 + t;
    int c = jj >> 6, off = (jj & 63) * 8;
    *(uint4*)&hs[c * LSTR + off] =
        *(const uint4*)(hT + ((long)b * CC + c) * NN + off);
  }

  // writeback step 0 + fp8 emit
#pragma unroll
  for (int j = 0; j < 8; ++j) {
    char* lp = (char*)at + swb + j * 4096;
    s4v bv;
    bv[0] = (short)f2bf(ar[j].x); bv[1] = (short)f2bf(ar[j].y);
    bv[2] = (short)f2bf(ar[j].z); bv[3] = (short)f2bf(ar[j].w);
    *(s4v*)lp = bv;
    int w0 = __builtin_amdgcn_cvt_pk_fp8_f32(ar[j].x * sc, ar[j].y * sc, 0, false);
    w0 = __builtin_amdgcn_cvt_pk_fp8_f32(ar[j].z * sc, ar[j].w * sc, w0, true);
    *(int*)(gao + (long)j * 8 * NN) = w0;
  }
  __syncthreads();

  // compute geometry: 8 waves = 4 row-tiles x 2 c-halves
  int wv = t >> 6, l = t & 63, lo = l & 15, q = l >> 4;
  int tile = wv & 3, half = wv >> 2;
  int lrow = tile * 16 + lo;
  const unsigned short* h0 = &hs[(half * 16 + lo) * LSTR + q * 8];

  v4f acc = {0.f, 0.f, 0.f, 0.f};

  for (int step = 0; step < 8; ++step) {
    uint4 hreg[4];
    if (step < 7) {
#pragma unroll
      for (int j = 0; j < 8; ++j)
        ar[j] = *(const float4*)(ga + (long)j * 8 * NN + (step + 1) * KS2);
      if (step & 1) {   // prefetch next hs slice (L2/L3-resident) into regs
        int qm = (step + 1) >> 1;
#pragma unroll
        for (int i = 0; i < 4; ++i) {
          int jj = i * 512 + t;
          int c = jj >> 6, off = (jj & 63) * 8;
          hreg[i] = *(const uint4*)(hT + ((long)b * CC + c) * NN + qm * QM + off);
        }
      }
    }
    int mloc = (step & 1) * KS2;     // column offset within current hs slice
#pragma unroll
    for (int kk = 0; kk < 8; ++kk) {
      short8 af = *(const short8*)((const char*)at + lrow * 512 +
                                   ((q * 16 + kk * 64) ^ ((lo & 7) << 4)));
      short8 bf = *(const short8*)(h0 + mloc + kk * 32);
      acc = __builtin_amdgcn_mfma_f32_16x16x32_bf16(af, bf, acc, 0, 0, 0);
    }
    if (step < 7) {
      __syncthreads();               // all waves done reading at (and hs)
#pragma unroll
      for (int j = 0; j < 8; ++j) {
        char* lp = (char*)at + swb + j * 4096;
        s4v bv;
        bv[0] = (short)f2bf(ar[j].x); bv[1] = (short)f2bf(ar[j].y);
        bv[2] = (short)f2bf(ar[j].z); bv[3] = (short)f2bf(ar[j].w);
        *(s4v*)lp = bv;
        int w0 = __builtin_amdgcn_cvt_pk_fp8_f32(ar[j].x * sc, ar[j].y * sc, 0, false);
        w0 = __builtin_amdgcn_cvt_pk_fp8_f32(ar[j].z * sc, ar[j].w * sc, w0, true);
        *(int*)(gao + (long)j * 8 * NN + (step + 1) * KS2) = w0;
      }
      if (step & 1) {
#pragma unroll
        for (int i = 0; i < 4; ++i) {
          int jj = i * 512 + t;
          int c = jj >> 6, off = (jj & 63) * 8;
          *(uint4*)&hs[c * LSTR + off] = hreg[i];
        }
      }
      __syncthreads();
    }
  }

  // ---- fused xw2 epilogue -------------------------------------------------
  __syncthreads();                    // everyone done reading hs/at
  float* hrow = (float*)hs;           // reuse hs as [64][33] f32
  float bc = b1[half * 16 + lo];
#pragma unroll
  for (int r = 0; r < 4; ++r)
    hrow[(tile * 16 + q * 4 + r) * 33 + half * 16 + lo] = elu1(acc[r] + bc);
  __syncthreads();

  short8 wf, af;
#pragma unroll
  for (int j = 0; j < 8; ++j) {
    wf[j] = (short)f2bf(w2[(q * 8 + j) * CC + half * 16 + lo]);
    af[j] = (short)f2bf(hrow[(tile * 16 + lo) * 33 + q * 8 + j]);
  }
  v4f acc2 = {0.f, 0.f, 0.f, 0.f};
  acc2 = __builtin_amdgcn_mfma_f32_16x16x32_bf16(af, wf, acc2, 0, 0, 0);

  const float inv = 1.f / 1024.f;
#pragma unroll
  for (int r = 0; r < 4; ++r) {
    int n = n0 + tile * 16 + q * 4 + r;
    hT2out[((long)b * CC + half * 16 + lo) * NN + n] = f2bf(acc2[r] * inv);
  }
}

// ---------------------------------------------------------------------------
// k_agg2f (R3, unchanged from R2 -- audited clean): FULL-K aggregation over
// afp8 + FUSED POOL, 512 threads (8 waves: 4 row-tiles x 2 c-halves),
// 16 waves/CU. Per quarter: stage 32 KB fp8 A-tile + 33 KB hT2 slice (both
// prefetched into regs under previous quarter's MFMAs), then 16 MFMAs/wave.
// Epilogue: elu(acc+b2), in-register pool reduce -> pp2[b][rt][32].
// grid = 512 x 512; LDS 65.8 KB.
// ---------------------------------------------------------------------------
__global__ __launch_bounds__(512, 4)
void k_agg2f(const unsigned char* __restrict__ afp8,
             const unsigned short* __restrict__ hT, const float* __restrict__ b2,
             float* __restrict__ pp2) {
  __shared__ __attribute__((aligned(16))) unsigned short hs[CC * LSTR];
  __shared__ __attribute__((aligned(16))) unsigned char a2[64 * QM];
  __shared__ float red[8][16];

  int t = threadIdx.x;
  int bid = blockIdx.x;
  int rt = bid & 31, b = bid >> 5;
  int n0 = rt * 64;

  // stage geometry: rr in 0..15, chunk in 0..31 (16-B units; 512 B per row)
  int rr = t >> 5, chunk = t & 31;
  const unsigned char* ga = afp8 + ((long)(b * NN + n0 + rr)) * NN + chunk * 16;
  char* lw = (char*)a2 + rr * 512 + ((chunk * 16) ^ ((rr & 7) << 4));

  uint4 arr[4];
#pragma unroll
  for (int j = 0; j < 4; ++j)
    arr[j] = *(const uint4*)(ga + (long)j * 16 * NN);
#pragma unroll
  for (int i = 0; i < 4; ++i) {
    int jj = i * 512 + t;
    int c = jj >> 6, off = (jj & 63) * 8;
    *(uint4*)&hs[c * LSTR + off] =
        *(const uint4*)(hT + ((long)b * CC + c) * NN + off);
  }
#pragma unroll
  for (int j = 0; j < 4; ++j)
    *(uint4*)(lw + j * 8192) = arr[j];
  __syncthreads();

  int wv = t >> 6, l = t & 63, lo = l & 15, q = l >> 4;
  int tile = wv & 3, half = wv >> 2;
  int lrow = tile * 16 + lo;
  const unsigned short* h0 = &hs[(half * 16 + lo) * LSTR + q * 8];

  v4f acc = {0.f, 0.f, 0.f, 0.f};

  for (int qm = 0; qm < 4; ++qm) {
    uint4 hreg[4];
    if (qm < 3) {
#pragma unroll
      for (int j = 0; j < 4; ++j)
        arr[j] = *(const uint4*)(ga + (long)j * 16 * NN + (qm + 1) * QM);
#pragma unroll
      for (int i = 0; i < 4; ++i) {
        int jj = i * 512 + t;
        int c = jj >> 6, off = (jj & 63) * 8;
        hreg[i] = *(const uint4*)(hT + ((long)b * CC + c) * NN +
                                  (qm + 1) * QM + off);
      }
    }
#pragma unroll
    for (int kk = 0; kk < 16; ++kk) {
      int2 av = *(const int2*)((const char*)a2 + lrow * 512 +
                               ((q * 8 + kk * 32) ^ ((lo & 7) << 4)));
      v2f f01 = __builtin_amdgcn_cvt_pk_f32_fp8(av.x, false);
      v2f f23 = __builtin_amdgcn_cvt_pk_f32_fp8(av.x, true);
      v2f f45 = __builtin_amdgcn_cvt_pk_f32_fp8(av.y, false);
      v2f f67 = __builtin_amdgcn_cvt_pk_f32_fp8(av.y, true);
      short8 af;
      af[0] = (short)f2bf(f01.x); af[1] = (short)f2bf(f01.y);
      af[2] = (short)f2bf(f23.x); af[3] = (short)f2bf(f23.y);
      af[4] = (short)f2bf(f45.x); af[5] = (short)f2bf(f45.y);
      af[6] = (short)f2bf(f67.x); af[7] = (short)f2bf(f67.y);
      short8 bf = *(const short8*)(h0 + kk * 32);
      acc = __builtin_amdgcn_mfma_f32_16x16x32_bf16(af, bf, acc, 0, 0, 0);
    }
    if (qm < 3) {
      __syncthreads();
#pragma unroll
      for (int j = 0; j < 4; ++j)
        *(uint4*)(lw + j * 8192) = arr[j];
#pragma unroll
      for (int i = 0; i < 4; ++i) {
        int jj = i * 512 + t;
        int c = jj >> 6, off = (jj & 63) * 8;
        *(uint4*)&hs[c * LSTR + off] = hreg[i];
      }
      __syncthreads();
    }
  }

  // epilogue: elu + fused global-sum-pool partial for this block's 64 rows
  float bc = b2[half * 16 + lo];
  float s = 0.f;
#pragma unroll
  for (int r = 0; r < 4; ++r) s += elu1(acc[r] + bc);
  s += __shfl_xor(s, 16);
  s += __shfl_xor(s, 32);
  if (l < 16) red[wv][lo] = s;
  __syncthreads();
  if (t < CC) {
    int h = t >> 4, c = t & 15;
    float p = red[h * 4 + 0][c] + red[h * 4 + 1][c] +
              red[h * 4 + 2][c] + red[h * 4 + 3][c];
    pp2[((long)b * 32 + rt) * CC + t] = p;
  }
}

// ---------------------------------------------------------------------------
// k5: out[b] = sigmoid( relu((sum_rt pp2)@wf1 + bf1) @ wf2 + bf2 )
// ---------------------------------------------------------------------------
__global__ __launch_bounds__(512)
void k5_mlp(const float* __restrict__ pp2, const float* __restrict__ wf1,
            const float* __restrict__ bf1, const float* __restrict__ wf2,
            const float* __restrict__ bf2, float* __restrict__ out) {
  __shared__ float red[HID];
  __shared__ float ps[CC];
  int b = blockIdx.x, j = threadIdx.x;
  if (j < CC) {
    float s = 0.f;
#pragma unroll
    for (int rt = 0; rt < 32; ++rt) s += pp2[((long)b * 32 + rt) * CC + j];
    ps[j] = s;
  }
  __syncthreads();
  float acc = bf1[j];
#pragma unroll
  for (int c = 0; c < CC; ++c) acc += ps[c] * wf1[c * HID + j];
  red[j] = fmaxf(acc, 0.f) * wf2[j];
  __syncthreads();
  for (int s = HID / 2; s > 0; s >>= 1) {
    if (j < s) red[j] += red[j + s];
    __syncthreads();
  }
  if (j == 0) out[b] = 1.f / (1.f + expf(-(red[0] + bf2[0])));
}

// ---------------------------------------------------------------------------
extern "C" void kernel_launch(void* const* d_in, const int* in_sizes, int n_in,
                              void* d_out, int out_size, void* d_ws, size_t ws_size,
                              hipStream_t stream) {
  const float* x   = (const float*)d_in[0];
  const float* a   = (const float*)d_in[1];
  const float* w1  = (const float*)d_in[2];
  const float* b1  = (const float*)d_in[3];
  const float* w2  = (const float*)d_in[4];
  const float* b2  = (const float*)d_in[5];
  const float* wf1 = (const float*)d_in[6];
  const float* bf1 = (const float*)d_in[7];
  const float* wf2 = (const float*)d_in[8];
  const float* bf2 = (const float*)d_in[9];
  float* out = (float*)d_out;

  char* ws = (char*)d_ws;
  unsigned char*  afp8 = (unsigned char*)ws;                   // 64 MB fp8 a
  unsigned short* hT1  = (unsigned short*)(ws + 0x4000000UL);  // 2 MB
  unsigned short* hT2  = (unsigned short*)(ws + 0x4200000UL);  // 2 MB
  float* pp2 = (float*)(ws + 0x4400000UL);                     // 64 KB

  k_xw1<<<512, 256, 0, stream>>>(x, w1, hT1);
  k_agg1f<<<512, 512, 0, stream>>>(a, afp8, hT1, b1, w2, hT2);
  k_agg2f<<<512, 512, 0, stream>>>(afp8, hT2, b2, pp2);
  k5_mlp<<<BATCH, HID, 0, stream>>>(pp2, wf1, bf1, wf2, bf2, out);
}

// Round 5
// 431.023 us; speedup vs baseline: 1.0502x; 1.0502x over previous
//
#include <hip/hip_runtime.h>
#include <hip/hip_bf16.h>
#include <math.h>

#define BATCH 16
#define NN 2048
#define FF 128
#define CC 32
#define HID 512
#define QM 512                 // m-columns per agg block (quarter of NN)
#define LSTR 520               // 512 + 8 pad (1040 B LDS row stride)
#define KS1 128                // agg1 K-step (columns per staged A tile)

typedef float v4f __attribute__((ext_vector_type(4)));
typedef float v2f __attribute__((ext_vector_type(2)));
typedef short short8 __attribute__((ext_vector_type(8)));
typedef short s4v __attribute__((ext_vector_type(4)));

__device__ __forceinline__ unsigned short f2bf(float f) {
  unsigned u = __float_as_uint(f);
  u += 0x7fffu + ((u >> 16) & 1u);
  return (unsigned short)(u >> 16);
}

__device__ __forceinline__ float elu1(float x) {
  return x > 0.f ? x : expm1f(x);
}

// ---------------------------------------------------------------------------
// k_xw1: hT1[b][c][n] = bf16( x[row][0:128] @ w1[128][32] )
// ---------------------------------------------------------------------------
__global__ __launch_bounds__(256)
void k_xw1(const float* __restrict__ src, const float* __restrict__ w,
           unsigned short* __restrict__ outT) {
  int t = threadIdx.x;
  int wv = t >> 6, l = t & 63, lo = l & 15, q = l >> 4;
  int rowt = blockIdx.x * 4 + wv;
  long row = (long)rowt * 16 + lo;

  short8 wf[FF / 32][2];
#pragma unroll
  for (int kc = 0; kc < FF / 32; ++kc)
#pragma unroll
    for (int h = 0; h < 2; ++h) {
      short8 f;
#pragma unroll
      for (int j = 0; j < 8; ++j)
        f[j] = (short)f2bf(w[(kc * 32 + q * 8 + j) * CC + h * 16 + lo]);
      wf[kc][h] = f;
    }

  v4f acc0 = {0.f, 0.f, 0.f, 0.f}, acc1 = {0.f, 0.f, 0.f, 0.f};
#pragma unroll
  for (int kc = 0; kc < FF / 32; ++kc) {
    const float* sp = src + row * FF + kc * 32 + q * 8;
    float4 a0 = *(const float4*)sp;
    float4 a1 = *(const float4*)(sp + 4);
    short8 af;
    af[0] = (short)f2bf(a0.x); af[1] = (short)f2bf(a0.y);
    af[2] = (short)f2bf(a0.z); af[3] = (short)f2bf(a0.w);
    af[4] = (short)f2bf(a1.x); af[5] = (short)f2bf(a1.y);
    af[6] = (short)f2bf(a1.z); af[7] = (short)f2bf(a1.w);
    acc0 = __builtin_amdgcn_mfma_f32_16x16x32_bf16(af, wf[kc][0], acc0, 0, 0, 0);
    acc1 = __builtin_amdgcn_mfma_f32_16x16x32_bf16(af, wf[kc][1], acc1, 0, 0, 0);
  }

  int b = rowt >> 7;
  int nbase = (rowt & 127) * 16;
#pragma unroll
  for (int r = 0; r < 4; ++r) {
    int n = nbase + q * 4 + r;
    outT[((long)b * CC + lo) * NN + n] = f2bf(acc0[r]);
    outT[((long)b * CC + 16 + lo) * NN + n] = f2bf(acc1[r]);
  }
}

// ---------------------------------------------------------------------------
// k_agg1: h1p[qm][b][n][c] = sum_{m in quarter} a[b,n,m]*hT1[b,c,m]; also
// emits afp8 = e4m3(a * 1024).
// R1-best structure (432 us): A staged through LDS in 512-B-per-row coalesced
// bursts; fp8 emission at stage time (128-B contiguous stores). Double-
// buffered bf16 A tile, XOR-swizzled (byte ^= (row&7)<<4) for conflict-free
// ds_read_b128 MFMA fragments. 2048 blocks -> max request-stream parallelism
// (this beat every 512-block full-K variant: aggs are latency-limited).
// grid = 16b x 4qm x 32rt = 2048 blocks x 256 thr.
// ---------------------------------------------------------------------------
__global__ __launch_bounds__(256, 2)
void k_agg1(const float* __restrict__ a, unsigned char* __restrict__ afp8,
            const unsigned short* __restrict__ hT, float* __restrict__ hpart) {
  __shared__ __attribute__((aligned(16))) unsigned short hs[CC * LSTR];
  __shared__ __attribute__((aligned(16))) unsigned short at[2][64 * KS1];

  int t = threadIdx.x;
  int bid = blockIdx.x;
  int rt = bid & 31, qm = (bid >> 5) & 3, b = bid >> 7;
  int n0 = rt * 64;

  // stage-thread geometry: r0 in 0..7, chunk in 0..31 (per row: 32 x 16 B)
  int r0 = t >> 5, chunk = t & 31;
  const float* ga = a + ((long)(b * NN + n0 + r0)) * NN + qm * QM + chunk * 4;
  unsigned char* gao = afp8 + ((long)(b * NN + n0 + r0)) * NN + qm * QM + chunk * 4;
  int swb = r0 * 256 + ((chunk * 8) ^ (r0 << 4));   // swizzled LDS byte base

  float4 ar[8];
  const float sc = 1024.f;

  // ---- prologue: issue A loads for ks=0 (long latency first)
#pragma unroll
  for (int j = 0; j < 8; ++j)
    ar[j] = *(const float4*)(ga + (long)j * 8 * NN);

  // stage hT slice (1-KB contiguous bursts, L2-resident)
#pragma unroll
  for (int i = 0; i < 8; ++i) {
    int jj = i * 256 + t;
    int c = jj >> 6, off = (jj & 63) * 8;
    *(uint4*)&hs[c * LSTR + off] =
        *(const uint4*)(hT + ((long)b * CC + c) * NN + qm * QM + off);
  }

  // writeback ks=0 into buf0 + fp8 emit
#pragma unroll
  for (int j = 0; j < 8; ++j) {
    char* lp = (char*)&at[0][0] + swb + j * 2048;
    s4v bv;
    bv[0] = (short)f2bf(ar[j].x); bv[1] = (short)f2bf(ar[j].y);
    bv[2] = (short)f2bf(ar[j].z); bv[3] = (short)f2bf(ar[j].w);
    *(s4v*)lp = bv;
    int w0 = __builtin_amdgcn_cvt_pk_fp8_f32(ar[j].x * sc, ar[j].y * sc, 0, false);
    w0 = __builtin_amdgcn_cvt_pk_fp8_f32(ar[j].z * sc, ar[j].w * sc, w0, true);
    *(int*)(gao + (long)j * 8 * NN) = w0;
  }
  __syncthreads();

  // compute-thread geometry
  int l = t & 63, wv = t >> 6, lo = l & 15, q = l >> 4;
  int lrow = wv * 16 + lo;
  const unsigned short* h0 = &hs[lo * LSTR + q * 8];

  v4f acc0 = {0.f, 0.f, 0.f, 0.f}, acc1 = {0.f, 0.f, 0.f, 0.f};

#pragma unroll
  for (int ks = 0; ks < 4; ++ks) {
    // T14 split: issue next-step loads before compute
    if (ks < 3) {
#pragma unroll
      for (int j = 0; j < 8; ++j)
        ar[j] = *(const float4*)(ga + (long)j * 8 * NN + (ks + 1) * KS1);
    }
    const char* ab = (const char*)at + (ks & 1) * (64 * KS1 * 2);
#pragma unroll
    for (int kk = 0; kk < 4; ++kk) {
      short8 af = *(const short8*)(ab + lrow * 256 + ((q * 16 + kk * 64) ^ ((lo & 7) << 4)));
      int m = ks * KS1 + kk * 32;
      short8 b0 = *(const short8*)(h0 + m);
      short8 b1 = *(const short8*)(h0 + 16 * LSTR + m);
      acc0 = __builtin_amdgcn_mfma_f32_16x16x32_bf16(af, b0, acc0, 0, 0, 0);
      acc1 = __builtin_amdgcn_mfma_f32_16x16x32_bf16(af, b1, acc1, 0, 0, 0);
    }
    if (ks < 3) {
      char* lb = (char*)&at[(ks + 1) & 1][0];
#pragma unroll
      for (int j = 0; j < 8; ++j) {
        char* lp = lb + swb + j * 2048;
        s4v bv;
        bv[0] = (short)f2bf(ar[j].x); bv[1] = (short)f2bf(ar[j].y);
        bv[2] = (short)f2bf(ar[j].z); bv[3] = (short)f2bf(ar[j].w);
        *(s4v*)lp = bv;
        int w0 = __builtin_amdgcn_cvt_pk_fp8_f32(ar[j].x * sc, ar[j].y * sc, 0, false);
        w0 = __builtin_amdgcn_cvt_pk_fp8_f32(ar[j].z * sc, ar[j].w * sc, w0, true);
        *(int*)(gao + (long)j * 8 * NN + (ks + 1) * KS1) = w0;
      }
      __syncthreads();
    }
  }

  float* op = hpart + ((long)qm * BATCH * NN + (long)b * NN) * CC;
#pragma unroll
  for (int r = 0; r < 4; ++r) {
    int n = n0 + wv * 16 + q * 4 + r;
    op[(long)n * CC + lo] = acc0[r];
    op[(long)n * CC + 16 + lo] = acc1[r];
  }
}

// ---------------------------------------------------------------------------
// k_xw2: hT2[b][c][n] = bf16( 2^-10 * elu(sum_qm h1p + b1)[row] @ w2 )
// ---------------------------------------------------------------------------
__global__ __launch_bounds__(256)
void k_xw2(const float* __restrict__ h1p, const float* __restrict__ b1,
           const float* __restrict__ w2, unsigned short* __restrict__ outT) {
  const long QS = (long)BATCH * NN * CC;
  int t = threadIdx.x;
  int wv = t >> 6, l = t & 63, lo = l & 15, q = l >> 4;
  int rowt = blockIdx.x * 4 + wv;
  long row = (long)rowt * 16 + lo;

  short8 wf[2];
#pragma unroll
  for (int h = 0; h < 2; ++h) {
    short8 f;
#pragma unroll
    for (int j = 0; j < 8; ++j)
      f[j] = (short)f2bf(w2[(q * 8 + j) * CC + h * 16 + lo]);
    wf[h] = f;
  }

  const float* p = h1p + row * CC + q * 8;
  float s[8] = {0, 0, 0, 0, 0, 0, 0, 0};
#pragma unroll
  for (int qq = 0; qq < 4; ++qq) {
    float4 u0 = *(const float4*)(p + qq * QS);
    float4 u1 = *(const float4*)(p + qq * QS + 4);
    s[0] += u0.x; s[1] += u0.y; s[2] += u0.z; s[3] += u0.w;
    s[4] += u1.x; s[5] += u1.y; s[6] += u1.z; s[7] += u1.w;
  }
  short8 af;
#pragma unroll
  for (int j = 0; j < 8; ++j)
    af[j] = (short)f2bf(elu1(s[j] + b1[q * 8 + j]));

  v4f acc0 = {0.f, 0.f, 0.f, 0.f}, acc1 = {0.f, 0.f, 0.f, 0.f};
  acc0 = __builtin_amdgcn_mfma_f32_16x16x32_bf16(af, wf[0], acc0, 0, 0, 0);
  acc1 = __builtin_amdgcn_mfma_f32_16x16x32_bf16(af, wf[1], acc1, 0, 0, 0);

  const float inv = 1.f / 1024.f;
  int b = rowt >> 7;
  int nbase = (rowt & 127) * 16;
#pragma unroll
  for (int r = 0; r < 4; ++r) {
    int n = nbase + q * 4 + r;
    outT[((long)b * CC + lo) * NN + n] = f2bf(acc0[r] * inv);
    outT[((long)b * CC + 16 + lo) * NN + n] = f2bf(acc1[r] * inv);
  }
}

// ---------------------------------------------------------------------------
// k_agg2: h2p[qm][b][n][c] = sum_{m in quarter} afp8[b,n,m]*hT2[b,c,m].
// R1-best structure: full 64x512 fp8 quarter-tile (32 KB) staged once with
// 512-B row bursts, single barrier, swizzled 8-B LDS reads. 2048 blocks.
// ---------------------------------------------------------------------------
__global__ __launch_bounds__(256, 2)
void k_agg2(const unsigned char* __restrict__ afp8,
            const unsigned short* __restrict__ hT, float* __restrict__ hpart) {
  __shared__ __attribute__((aligned(16))) unsigned short hs[CC * LSTR];
  __shared__ __attribute__((aligned(16))) unsigned char a2[64 * QM];

  int t = threadIdx.x;
  int bid = blockIdx.x;
  int rt = bid & 31, qm = (bid >> 5) & 3, b = bid >> 7;
  int n0 = rt * 64;

  int r0 = t >> 5, chunk = t & 31;
  const unsigned char* ga =
      afp8 + ((long)(b * NN + n0 + r0)) * NN + qm * QM + chunk * 16;
  char* lw = (char*)a2 + r0 * 512 + ((chunk * 16) ^ (r0 << 4));

  uint4 arr[8];
#pragma unroll
  for (int j = 0; j < 8; ++j)
    arr[j] = *(const uint4*)(ga + (long)j * 8 * NN);

#pragma unroll
  for (int i = 0; i < 8; ++i) {
    int jj = i * 256 + t;
    int c = jj >> 6, off = (jj & 63) * 8;
    *(uint4*)&hs[c * LSTR + off] =
        *(const uint4*)(hT + ((long)b * CC + c) * NN + qm * QM + off);
  }

#pragma unroll
  for (int j = 0; j < 8; ++j)
    *(uint4*)(lw + j * 4096) = arr[j];
  __syncthreads();

  int l = t & 63, wv = t >> 6, lo = l & 15, q = l >> 4;
  int lrow = wv * 16 + lo;
  const unsigned short* h0 = &hs[lo * LSTR + q * 8];
  const char* ab = (const char*)a2;

  v4f acc0 = {0.f, 0.f, 0.f, 0.f}, acc1 = {0.f, 0.f, 0.f, 0.f};
#pragma unroll
  for (int kk = 0; kk < 16; ++kk) {
    int2 av = *(const int2*)(ab + lrow * 512 + ((q * 8 + kk * 32) ^ ((lo & 7) << 4)));
    v2f f01 = __builtin_amdgcn_cvt_pk_f32_fp8(av.x, false);
    v2f f23 = __builtin_amdgcn_cvt_pk_f32_fp8(av.x, true);
    v2f f45 = __builtin_amdgcn_cvt_pk_f32_fp8(av.y, false);
    v2f f67 = __builtin_amdgcn_cvt_pk_f32_fp8(av.y, true);
    short8 af;
    af[0] = (short)f2bf(f01.x); af[1] = (short)f2bf(f01.y);
    af[2] = (short)f2bf(f23.x); af[3] = (short)f2bf(f23.y);
    af[4] = (short)f2bf(f45.x); af[5] = (short)f2bf(f45.y);
    af[6] = (short)f2bf(f67.x); af[7] = (short)f2bf(f67.y);
    int m = kk * 32;
    short8 b0 = *(const short8*)(h0 + m);
    short8 b1 = *(const short8*)(h0 + 16 * LSTR + m);
    acc0 = __builtin_amdgcn_mfma_f32_16x16x32_bf16(af, b0, acc0, 0, 0, 0);
    acc1 = __builtin_amdgcn_mfma_f32_16x16x32_bf16(af, b1, acc1, 0, 0, 0);
  }

  float* op = hpart + ((long)qm * BATCH * NN + (long)b * NN) * CC;
#pragma unroll
  for (int r = 0; r < 4; ++r) {
    int n = n0 + wv * 16 + q * 4 + r;
    op[(long)n * CC + lo] = acc0[r];
    op[(long)n * CC + 16 + lo] = acc1[r];
  }
}

// ---------------------------------------------------------------------------
// k_pool: pp[seg][b][c] = sum_{n in seg} elu( sum_qm h2p + b2[c] ). No atomics.
// ---------------------------------------------------------------------------
__global__ __launch_bounds__(256)
void k_pool(const float* __restrict__ h2p, const float* __restrict__ b2,
            float* __restrict__ pp) {
  const long QS = (long)BATCH * NN * CC;
  __shared__ float red[8][CC + 1];
  int t = threadIdx.x;
  int b = blockIdx.x >> 3, seg = blockIdx.x & 7;
  int c = t & 31, nl = t >> 5;
  float bc = b2[c];
  float s = 0.f;
  for (int n = seg * 256 + nl; n < seg * 256 + 256; n += 8) {
    long idx = ((long)b * NN + n) * CC + c;
    s += elu1(h2p[idx] + h2p[QS + idx] + h2p[2 * QS + idx] + h2p[3 * QS + idx] + bc);
  }
  red[nl][c] = s;
  __syncthreads();
  if (nl < 4) red[nl][c] += red[nl + 4][c];
  __syncthreads();
  if (nl < 2) red[nl][c] += red[nl + 2][c];
  __syncthreads();
  if (nl == 0) pp[((long)seg * BATCH + b) * CC + c] = red[0][c] + red[1][c];
}

// ---------------------------------------------------------------------------
// k5: out[b] = sigmoid( relu((sum_seg pp)@wf1 + bf1) @ wf2 + bf2 )
// ---------------------------------------------------------------------------
__global__ __launch_bounds__(512)
void k5_mlp(const float* __restrict__ pp, const float* __restrict__ wf1,
            const float* __restrict__ bf1, const float* __restrict__ wf2,
            const float* __restrict__ bf2, float* __restrict__ out) {
  __shared__ float red[HID];
  __shared__ float ps[CC];
  int b = blockIdx.x, j = threadIdx.x;
  if (j < CC) {
    float s = 0.f;
#pragma unroll
    for (int g = 0; g < 8; ++g) s += pp[((long)g * BATCH + b) * CC + j];
    ps[j] = s;
  }
  __syncthreads();
  float acc = bf1[j];
#pragma unroll
  for (int c = 0; c < CC; ++c) acc += ps[c] * wf1[c * HID + j];
  red[j] = fmaxf(acc, 0.f) * wf2[j];
  __syncthreads();
  for (int s = HID / 2; s > 0; s >>= 1) {
    if (j < s) red[j] += red[j + s];
    __syncthreads();
  }
  if (j == 0) out[b] = 1.f / (1.f + expf(-(red[0] + bf2[0])));
}

// ---------------------------------------------------------------------------
extern "C" void kernel_launch(void* const* d_in, const int* in_sizes, int n_in,
                              void* d_out, int out_size, void* d_ws, size_t ws_size,
                              hipStream_t stream) {
  const float* x   = (const float*)d_in[0];
  const float* a   = (const float*)d_in[1];
  const float* w1  = (const float*)d_in[2];
  const float* b1  = (const float*)d_in[3];
  const float* w2  = (const float*)d_in[4];
  const float* b2  = (const float*)d_in[5];
  const float* wf1 = (const float*)d_in[6];
  const float* bf1 = (const float*)d_in[7];
  const float* wf2 = (const float*)d_in[8];
  const float* bf2 = (const float*)d_in[9];
  float* out = (float*)d_out;

  char* ws = (char*)d_ws;
  unsigned char*  afp8 = (unsigned char*)ws;                   // 64 MB fp8 a
  unsigned short* hT1  = (unsigned short*)(ws + 0x4000000UL);  // 2 MB
  unsigned short* hT2  = (unsigned short*)(ws + 0x4200000UL);  // 2 MB
  float* h1p = (float*)(ws + 0x4400000UL);                     // 16 MB
  float* h2p = (float*)(ws + 0x5400000UL);                     // 16 MB
  float* pp  = (float*)(ws + 0x6400000UL);                     // 16 KB

  k_xw1<<<512, 256, 0, stream>>>(x, w1, hT1);
  k_agg1<<<2048, 256, 0, stream>>>(a, afp8, hT1, h1p);
  k_xw2<<<512, 256, 0, stream>>>(h1p, b1, w2, hT2);
  k_agg2<<<2048, 256, 0, stream>>>(afp8, hT2, h2p);
  k_pool<<<128, 256, 0, stream>>>(h2p, b2, pp);
  k5_mlp<<<BATCH, HID, 0, stream>>>(pp, wf1, bf1, wf2, bf2, out);
}